// Round 3
// baseline (581.461 us; speedup 1.0000x reference)
//
#include <hip/hip_runtime.h>
#include <math.h>

// MoE router: logits -> top-2 -> softmax -> capacity-ranked dispatch.
// Output layout (all float32, concatenated):
//   used_capacity[E], cb_weight[N*E*C], sec_mask[N*E*C].
//
// R7: R6's fused write_all ran at 4.3 TB/s (VALU-issue-bound: ~16 instr per
//   32B stored -- per-element expert/rank math + LDS reads in the hot loop).
//   Restructure: unconditional zero-stream (pure float4 stores, ~5 instr/32B,
//   store-bound) -> __syncthreads (drains block stores) -> thread 0 rewrites
//   the token's <=2 nonzero cells. Same 537MB, fill-rate streaming.
//
//   K1 logits_topk: per-token logits + top-2 + 2-way softmax (unchanged)
//   K2 rank:        ONE workgroup: ballot counts -> per-expert scan ->
//                   global rank per slot + used_cap (unchanged from R6)
//   K3 write_all:   one block per token; zero-stream 8*C floats of cb and
//                   sec, then fixup the <=2 nonzeros after a barrier.

#define HDIM 1024
#define NEXP 8

__global__ __launch_bounds__(256) void logits_topk_kernel(
    const float* __restrict__ x, const float* __restrict__ wg,
    int* __restrict__ expert_slot, float* __restrict__ prob_slot, int N) {
  __shared__ float w_lds[NEXP * HDIM];  // 32 KB
  const int tid = threadIdx.x;
  for (int i = tid; i < NEXP * HDIM / 4; i += blockDim.x)
    ((float4*)w_lds)[i] = ((const float4*)wg)[i];
  __syncthreads();

  const int wave = tid >> 6;
  const int lane = tid & 63;
  const int n = blockIdx.x * 4 + wave;
  if (n >= N) return;

  const float* xr = x + (size_t)n * HDIM;
  float acc[NEXP];
#pragma unroll
  for (int e = 0; e < NEXP; e++) acc[e] = 0.0f;

  // lane reads float4 at j + lane*4; 4 iterations cover HDIM=1024.
#pragma unroll
  for (int j = 0; j < HDIM; j += 256) {
    float4 xv = ((const float4*)(xr + j))[lane];
#pragma unroll
    for (int e = 0; e < NEXP; e++) {
      float4 wv = ((const float4*)(w_lds + e * HDIM + j))[lane];
      acc[e] += xv.x * wv.x + xv.y * wv.y + xv.z * wv.z + xv.w * wv.w;
    }
  }

#pragma unroll
  for (int e = 0; e < NEXP; e++) {
    float v = acc[e];
    for (int off = 32; off > 0; off >>= 1) v += __shfl_down(v, off, 64);
    acc[e] = v;
  }

  if (lane == 0) {
    // top-2, ties -> lower index (matches lax.top_k)
    int b0 = 0;
    float v0 = acc[0];
#pragma unroll
    for (int e = 1; e < NEXP; e++) {
      if (acc[e] > v0) { v0 = acc[e]; b0 = e; }
    }
    int b1 = -1;
    float v1 = -INFINITY;
#pragma unroll
    for (int e = 0; e < NEXP; e++) {
      if (e == b0) continue;
      if (acc[e] > v1) { v1 = acc[e]; b1 = e; }
    }
    float e2 = expf(v1 - v0);
    float p0 = 1.0f / (1.0f + e2);
    float p1 = e2 / (1.0f + e2);
    expert_slot[n] = b0;
    expert_slot[N + n] = b1;
    prob_slot[n] = p0;
    prob_slot[N + n] = p1;
  }
}

// K2: single workgroup, 1024 threads (16 waves). S = 2N slots, k-major
// (slot s = k*N + n, matching the reference cumsum order).
#define MAXCHUNK 128
__global__ __launch_bounds__(1024) void rank_kernel(
    const int* __restrict__ expert_slot, int* __restrict__ rank_slot,
    float* __restrict__ used_cap, int S, int C) {
  __shared__ int cnt[MAXCHUNK * 9];
  __shared__ int base[MAXCHUNK * 9];
  const int tid = threadIdx.x;
  const int wave = tid >> 6;  // 0..15
  const int lane = tid & 63;
  const int nchunk = (S + 63) >> 6;  // 128 for S=8192 (must be <= MAXCHUNK)

  // pass 1: counts per chunk per expert
  for (int c = wave; c < nchunk; c += 16) {
    const int s = c * 64 + lane;
    const int e = (s < S) ? expert_slot[s] : -1;
#pragma unroll
    for (int w = 0; w < NEXP; w++) {
      unsigned long long m = __ballot(e == w);
      if (lane == w) cnt[c * 9 + w] = __popcll(m);
    }
  }
  __syncthreads();

  // pass 2: exclusive scan over chunks, one expert per wave (nchunk <= 128)
  if (wave < NEXP) {
    const int w = wave;
    int v0 = (lane < nchunk) ? cnt[lane * 9 + w] : 0;
    int s0 = v0;
    for (int off = 1; off < 64; off <<= 1) {
      int t = __shfl_up(s0, off, 64);
      if (lane >= off) s0 += t;
    }
    int total0 = __shfl(s0, 63, 64);
    if (lane < nchunk) base[lane * 9 + w] = s0 - v0;

    const int i1 = 64 + lane;
    int v1 = (i1 < nchunk) ? cnt[i1 * 9 + w] : 0;
    int s1 = v1;
    for (int off = 1; off < 64; off <<= 1) {
      int t = __shfl_up(s1, off, 64);
      if (lane >= off) s1 += t;
    }
    if (i1 < nchunk) base[i1 * 9 + w] = total0 + s1 - v1;
    int total = total0 + __shfl(s1, 63, 64);
    if (lane == 0) used_cap[w] = (float)(total < C ? total : C);
  }
  __syncthreads();

  // pass 3: global rank per slot
  for (int c = wave; c < nchunk; c += 16) {
    const int s = c * 64 + lane;
    const int e = (s < S) ? expert_slot[s] : -1;
    const unsigned long long below = (1ull << lane) - 1ull;
    int rank = -1;
#pragma unroll
    for (int w = 0; w < NEXP; w++) {
      unsigned long long m = __ballot(e == w);
      if (e == w) rank = base[c * 9 + w] + __popcll(m & below);
    }
    if (s < S) rank_slot[s] = rank;
  }
}

// K3: one block per token n. Phase 1: unconditional zero-stream of the
// token's 8*C floats in cb and sec (pure float4 stores -> fill rate).
// Phase 2 (after barrier): thread 0 overwrites the <=2 nonzero cells.
__global__ __launch_bounds__(256) void write_all_kernel(
    const int* __restrict__ expert_slot, const float* __restrict__ prob_slot,
    const int* __restrict__ rank_slot, float* __restrict__ cb,
    float* __restrict__ sec, int N, int C) {
  const int n = blockIdx.x;
  float4* __restrict__ cbp = (float4*)(cb + (size_t)n * NEXP * C);
  float4* __restrict__ secp = (float4*)(sec + (size_t)n * NEXP * C);
  const int span4 = (NEXP * C) >> 2;  // 4096 float4s for C=2048

  const float4 z = {0.0f, 0.0f, 0.0f, 0.0f};
#pragma unroll 4
  for (int i = threadIdx.x; i < span4; i += 256) {
    cbp[i] = z;
    secp[i] = z;
  }
  __syncthreads();  // drains this block's stores (vmcnt(0) before barrier)

  if (threadIdx.x == 0) {
#pragma unroll
    for (int k = 0; k < 2; k++) {
      const int s = k * N + n;
      const int e = expert_slot[s];
      const int r = rank_slot[s];
      if (r < C) {
        const float p = prob_slot[s];
        const size_t off = (size_t)e * C + r;
        ((float*)cbp)[off] = p;
        ((float*)secp)[off] = (p != 0.0f) ? 1.0f : 0.0f;
      }
    }
  }
}

extern "C" void kernel_launch(void* const* d_in, const int* in_sizes, int n_in,
                              void* d_out, int out_size, void* d_ws, size_t ws_size,
                              hipStream_t stream) {
  const float* x = (const float*)d_in[0];
  const float* wg = (const float*)d_in[1];

  const int N = in_sizes[0] / HDIM;  // 4096 tokens
  const int K = 2;
  int capacity = (int)floor((double)K * 2.0 * (double)N / (double)NEXP);
  if (capacity < 4) capacity = 4;

  const int S = 2 * N;

  float* out = (float*)d_out;
  float* used_cap = out;
  float* cb = out + NEXP;
  float* sec = cb + (size_t)N * NEXP * (size_t)capacity;

  char* ws = (char*)d_ws;
  int* expert_slot = (int*)ws;                      // S ints
  float* prob_slot = (float*)(ws + 4 * (size_t)S);  // S floats
  int* rank_slot = (int*)(ws + 8 * (size_t)S);      // S ints

  logits_topk_kernel<<<(N + 3) / 4, 256, 0, stream>>>(x, wg, expert_slot,
                                                      prob_slot, N);
  rank_kernel<<<1, 1024, 0, stream>>>(expert_slot, rank_slot, used_cap, S,
                                      capacity);
  write_all_kernel<<<N, 256, 0, stream>>>(expert_slot, prob_slot, rank_slot,
                                          cb, sec, N, capacity);
}

// Round 4
// 543.643 us; speedup vs baseline: 1.0696x; 1.0696x over previous
//
#include <hip/hip_runtime.h>
#include <math.h>

// MoE router: logits -> top-2 -> softmax -> capacity-ranked dispatch.
// Output layout (all float32, concatenated):
//   used_capacity[E], cb_weight[N*E*C], sec_mask[N*E*C].
//
// R8: REVERT to hipMemsetAsync for the 537MB zero + fuse everything after
//   logits into one single-workgroup kernel.
//   Evidence (R6/R7): in-kernel streaming of the 537MB (two write streams,
//   cb+sec) runs at only ~3.5 TB/s, while rocclr fillBufferAligned sustains
//   6.2 TB/s write-only on the same bytes. Writing the zeros ourselves cost
//   +60..70us vs the fill path. So: let the fill do the bulk bytes.
//   Dispatches (3 + fill):
//   M  hipMemsetAsync: zero 537MB of d_out at fill rate (~87us, mandatory)
//   K1 logits_topk:    per-token logits + top-2 + 2-way softmax (unchanged)
//   K2 rank_scatter:   ONE workgroup (1024 thr): ballot counts -> per-expert
//                      shfl scan (base + used_cap) -> global rank -> scatter
//                      the ~8192 nonzeros directly (no rank_slot round-trip).

#define HDIM 1024
#define NEXP 8

__global__ __launch_bounds__(256) void logits_topk_kernel(
    const float* __restrict__ x, const float* __restrict__ wg,
    int* __restrict__ expert_slot, float* __restrict__ prob_slot, int N) {
  __shared__ float w_lds[NEXP * HDIM];  // 32 KB
  const int tid = threadIdx.x;
  for (int i = tid; i < NEXP * HDIM / 4; i += blockDim.x)
    ((float4*)w_lds)[i] = ((const float4*)wg)[i];
  __syncthreads();

  const int wave = tid >> 6;
  const int lane = tid & 63;
  const int n = blockIdx.x * 4 + wave;
  if (n >= N) return;

  const float* xr = x + (size_t)n * HDIM;
  float acc[NEXP];
#pragma unroll
  for (int e = 0; e < NEXP; e++) acc[e] = 0.0f;

  // lane reads float4 at j + lane*4; 4 iterations cover HDIM=1024.
#pragma unroll
  for (int j = 0; j < HDIM; j += 256) {
    float4 xv = ((const float4*)(xr + j))[lane];
#pragma unroll
    for (int e = 0; e < NEXP; e++) {
      float4 wv = ((const float4*)(w_lds + e * HDIM + j))[lane];
      acc[e] += xv.x * wv.x + xv.y * wv.y + xv.z * wv.z + xv.w * wv.w;
    }
  }

#pragma unroll
  for (int e = 0; e < NEXP; e++) {
    float v = acc[e];
    for (int off = 32; off > 0; off >>= 1) v += __shfl_down(v, off, 64);
    acc[e] = v;
  }

  if (lane == 0) {
    // top-2, ties -> lower index (matches lax.top_k)
    int b0 = 0;
    float v0 = acc[0];
#pragma unroll
    for (int e = 1; e < NEXP; e++) {
      if (acc[e] > v0) { v0 = acc[e]; b0 = e; }
    }
    int b1 = -1;
    float v1 = -INFINITY;
#pragma unroll
    for (int e = 0; e < NEXP; e++) {
      if (e == b0) continue;
      if (acc[e] > v1) { v1 = acc[e]; b1 = e; }
    }
    float e2 = expf(v1 - v0);
    float p0 = 1.0f / (1.0f + e2);
    float p1 = e2 / (1.0f + e2);
    expert_slot[n] = b0;
    expert_slot[N + n] = b1;
    prob_slot[n] = p0;
    prob_slot[N + n] = p1;
  }
}

// K2: single workgroup, 1024 threads (16 waves). S = 2N slots, k-major
// (slot s = k*N + n, matching the reference cumsum order: k*N+n ordering).
//   pass 1: per-64-slot-chunk per-expert counts via ballot -> LDS
//   pass 2: waves 0..7: exclusive scan of 128 chunk counts of their expert
//           (two 64-lane shfl rounds); used_cap[e] = min(total, C).
//   pass 3: rank = chunk base + intra-chunk ballot prefix; scatter the
//           <=2 nonzero cells per token straight into cb/sec.
// LDS arrays padded to stride 9 to break the 8-stride bank pattern.
#define MAXCHUNK 128
__global__ __launch_bounds__(1024) void rank_scatter_kernel(
    const int* __restrict__ expert_slot, const float* __restrict__ prob_slot,
    float* __restrict__ used_cap, float* __restrict__ cb,
    float* __restrict__ sec, int N, int C) {
  __shared__ int cnt[MAXCHUNK * 9];
  __shared__ int base[MAXCHUNK * 9];
  const int S = 2 * N;
  const int tid = threadIdx.x;
  const int wave = tid >> 6;  // 0..15
  const int lane = tid & 63;
  const int nchunk = (S + 63) >> 6;  // 128 for S=8192 (must be <= MAXCHUNK)

  // pass 1: counts per chunk per expert
  for (int c = wave; c < nchunk; c += 16) {
    const int s = c * 64 + lane;
    const int e = (s < S) ? expert_slot[s] : -1;
#pragma unroll
    for (int w = 0; w < NEXP; w++) {
      unsigned long long m = __ballot(e == w);
      if (lane == w) cnt[c * 9 + w] = __popcll(m);
    }
  }
  __syncthreads();

  // pass 2: exclusive scan over chunks, one expert per wave (nchunk <= 128)
  if (wave < NEXP) {
    const int w = wave;
    int v0 = (lane < nchunk) ? cnt[lane * 9 + w] : 0;
    int s0 = v0;
    for (int off = 1; off < 64; off <<= 1) {
      int t = __shfl_up(s0, off, 64);
      if (lane >= off) s0 += t;
    }
    int total0 = __shfl(s0, 63, 64);
    if (lane < nchunk) base[lane * 9 + w] = s0 - v0;

    const int i1 = 64 + lane;
    int v1 = (i1 < nchunk) ? cnt[i1 * 9 + w] : 0;
    int s1 = v1;
    for (int off = 1; off < 64; off <<= 1) {
      int t = __shfl_up(s1, off, 64);
      if (lane >= off) s1 += t;
    }
    if (i1 < nchunk) base[i1 * 9 + w] = total0 + s1 - v1;
    int total = total0 + __shfl(s1, 63, 64);
    if (lane == 0) used_cap[w] = (float)(total < C ? total : C);
  }
  __syncthreads();

  // pass 3: global rank per slot + direct scatter of the nonzeros
  for (int c = wave; c < nchunk; c += 16) {
    const int s = c * 64 + lane;
    const int e = (s < S) ? expert_slot[s] : -1;
    const unsigned long long below = (1ull << lane) - 1ull;
    int rank = -1;
#pragma unroll
    for (int w = 0; w < NEXP; w++) {
      unsigned long long m = __ballot(e == w);
      if (e == w) rank = base[c * 9 + w] + __popcll(m & below);
    }
    if (s < S && rank >= 0 && rank < C) {
      const float p = prob_slot[s];
      const int n = (s >= N) ? (s - N) : s;
      const size_t off = ((size_t)n * NEXP + e) * (size_t)C + (size_t)rank;
      cb[off] = p;
      sec[off] = (p != 0.0f) ? 1.0f : 0.0f;
    }
  }
}

extern "C" void kernel_launch(void* const* d_in, const int* in_sizes, int n_in,
                              void* d_out, int out_size, void* d_ws, size_t ws_size,
                              hipStream_t stream) {
  const float* x = (const float*)d_in[0];
  const float* wg = (const float*)d_in[1];

  const int N = in_sizes[0] / HDIM;  // 4096 tokens
  const int K = 2;
  int capacity = (int)floor((double)K * 2.0 * (double)N / (double)NEXP);
  if (capacity < 4) capacity = 4;

  const int S = 2 * N;

  float* out = (float*)d_out;
  float* used_cap = out;
  float* cb = out + NEXP;
  float* sec = cb + (size_t)N * NEXP * (size_t)capacity;

  char* ws = (char*)d_ws;
  int* expert_slot = (int*)ws;                      // S ints
  float* prob_slot = (float*)(ws + 4 * (size_t)S);  // S floats

  // Zero exactly the logical output: 4*(8 + 2*N*NEXP*C) = 536.9 MB, via the
  // rocclr fill path (6.2 TB/s write-only; our own streaming stores only
  // reached ~3.5 TB/s in R6/R7 -- see header comment).
  const size_t out_bytes =
      sizeof(float) * ((size_t)NEXP +
                       2ull * (size_t)N * (size_t)NEXP * (size_t)capacity);
  hipMemsetAsync(d_out, 0, out_bytes, stream);

  logits_topk_kernel<<<(N + 3) / 4, 256, 0, stream>>>(x, wg, expert_slot,
                                                      prob_slot, N);
  rank_scatter_kernel<<<1, 1024, 0, stream>>>(expert_slot, prob_slot, used_cap,
                                              cb, sec, N, capacity);
}

// Round 5
// 534.251 us; speedup vs baseline: 1.0884x; 1.0176x over previous
//
#include <hip/hip_runtime.h>
#include <math.h>

// MoE router: logits -> top-2 -> softmax -> capacity-ranked dispatch.
// Output layout (all float32, concatenated):
//   used_capacity[E], cb_weight[N*E*C], sec_mask[N*E*C].
//
// R9: revert to the R5 structure -- the best measured (530.9us). Session
// findings that pin this as the optimum of everything tried:
//   - The 2.147GB/348us fill in every profile is the HARNESS poison of the
//     4x-padded output allocation, inside the timed window. Uncontrollable.
//   - Our own 537MB zero MUST go through hipMemsetAsync: the rocclr fill
//     sustains 6.2 TB/s; in-kernel float4 streaming of the same bytes only
//     reached ~3.5 TB/s (R6/R7, two structures tried: +40..50us each).
//   - Dispatch count does not matter (5 vs 3 dispatches: no delta) -- the
//     ~90us non-kernel residual is fixed harness overhead.
//   - The scatter must be grid-parallel: single-workgroup scatter (R8) lost
//     ~12us to single-CU store latency on ~16K scattered 4B stores.
//
//   M  hipMemsetAsync: zero 537MB of d_out at fill rate (~87us, mandatory)
//   K1 logits_topk:  per-token logits + top-2 + 2-way softmax (float4 loads)
//   K2 count:        per-64-slot-chunk per-expert counts via ballot (parallel)
//   K3 scan:         exclusive scan of chunk counts per expert (8 waves, shfl)
//   K4 scatter:      wave per chunk: intra-chunk rank via ballot + chunk base,
//                    write the ~8192x2 nonzeros; used_capacity from K3.

#define HDIM 1024
#define NEXP 8

__global__ __launch_bounds__(256) void logits_topk_kernel(
    const float* __restrict__ x, const float* __restrict__ wg,
    int* __restrict__ expert_slot, float* __restrict__ prob_slot, int N) {
  __shared__ float w_lds[NEXP * HDIM];  // 32 KB
  const int tid = threadIdx.x;
  for (int i = tid; i < NEXP * HDIM / 4; i += blockDim.x)
    ((float4*)w_lds)[i] = ((const float4*)wg)[i];
  __syncthreads();

  const int wave = tid >> 6;
  const int lane = tid & 63;
  const int n = blockIdx.x * 4 + wave;
  if (n >= N) return;

  const float* xr = x + (size_t)n * HDIM;
  float acc[NEXP];
#pragma unroll
  for (int e = 0; e < NEXP; e++) acc[e] = 0.0f;

  // lane reads float4 at j + lane*4; 4 iterations cover HDIM=1024.
#pragma unroll
  for (int j = 0; j < HDIM; j += 256) {
    float4 xv = ((const float4*)(xr + j))[lane];
#pragma unroll
    for (int e = 0; e < NEXP; e++) {
      float4 wv = ((const float4*)(w_lds + e * HDIM + j))[lane];
      acc[e] += xv.x * wv.x + xv.y * wv.y + xv.z * wv.z + xv.w * wv.w;
    }
  }

#pragma unroll
  for (int e = 0; e < NEXP; e++) {
    float v = acc[e];
    for (int off = 32; off > 0; off >>= 1) v += __shfl_down(v, off, 64);
    acc[e] = v;
  }

  if (lane == 0) {
    // top-2, ties -> lower index (matches lax.top_k)
    int b0 = 0;
    float v0 = acc[0];
#pragma unroll
    for (int e = 1; e < NEXP; e++) {
      if (acc[e] > v0) { v0 = acc[e]; b0 = e; }
    }
    int b1 = -1;
    float v1 = -INFINITY;
#pragma unroll
    for (int e = 0; e < NEXP; e++) {
      if (e == b0) continue;
      if (acc[e] > v1) { v1 = acc[e]; b1 = e; }
    }
    float e2 = expf(v1 - v0);
    float p0 = 1.0f / (1.0f + e2);
    float p1 = e2 / (1.0f + e2);
    expert_slot[n] = b0;
    expert_slot[N + n] = b1;
    prob_slot[n] = p0;
    prob_slot[N + n] = p1;
  }
}

// K2: one wave per 64-slot chunk; counts[chunk*NEXP + w] = #matches.
__global__ __launch_bounds__(256) void count_kernel(
    const int* __restrict__ expert_slot, int* __restrict__ counts, int S) {
  const int gid = blockIdx.x * 256 + threadIdx.x;
  const int wave = gid >> 6;  // chunk id
  const int lane = gid & 63;
  const int s = wave * 64 + lane;
  if (s >= S) return;
  const int e = expert_slot[s];
#pragma unroll
  for (int w = 0; w < NEXP; w++) {
    unsigned long long m = __ballot(e == w);
    if (lane == w) counts[wave * NEXP + w] = __popcll(m);
  }
}

// K3: 8 waves; wave w scans 128 chunk counts of expert w (two 64-lane rounds).
// Writes exclusive base[chunk*NEXP+w] and used_cap[w] = min(total, C).
__global__ __launch_bounds__(512) void scan_kernel(
    const int* __restrict__ counts, int* __restrict__ base,
    float* __restrict__ used_cap, int nchunk, int C) {
  const int w = threadIdx.x >> 6;
  const int lane = threadIdx.x & 63;

  int v0 = (lane < nchunk) ? counts[lane * NEXP + w] : 0;
  int s0 = v0;
  for (int off = 1; off < 64; off <<= 1) {
    int t = __shfl_up(s0, off, 64);
    if (lane >= off) s0 += t;
  }
  int total0 = __shfl(s0, 63, 64);
  if (lane < nchunk) base[lane * NEXP + w] = s0 - v0;

  int i1 = 64 + lane;
  int v1 = (i1 < nchunk) ? counts[i1 * NEXP + w] : 0;
  int s1 = v1;
  for (int off = 1; off < 64; off <<= 1) {
    int t = __shfl_up(s1, off, 64);
    if (lane >= off) s1 += t;
  }
  if (i1 < nchunk) base[i1 * NEXP + w] = total0 + s1 - v1;
  int total = total0 + __shfl(s1, 63, 64);
  if (lane == 0) used_cap[w] = (float)(total < C ? total : C);
}

// K4: one wave per chunk; rank = base[chunk][e] + intra-chunk ballot prefix.
__global__ __launch_bounds__(256) void scatter_kernel(
    const int* __restrict__ expert_slot, const float* __restrict__ prob_slot,
    const int* __restrict__ base, float* __restrict__ cb,
    float* __restrict__ sec, int N, int C) {
  const int gid = blockIdx.x * 256 + threadIdx.x;
  const int wave = gid >> 6;  // chunk id
  const int lane = gid & 63;
  const int s = wave * 64 + lane;
  if (s >= 2 * N) return;
  const int e = expert_slot[s];
  const float p = prob_slot[s];
  const unsigned long long below = (1ull << lane) - 1ull;
  int rank = -1;
#pragma unroll
  for (int w = 0; w < NEXP; w++) {
    unsigned long long m = __ballot(e == w);
    if (e == w) rank = base[wave * NEXP + w] + __popcll(m & below);
  }
  if (rank < C) {
    int n = (s >= N) ? (s - N) : s;
    size_t off = ((size_t)n * NEXP + e) * (size_t)C + (size_t)rank;
    cb[off] = p;
    sec[off] = (p != 0.0f) ? 1.0f : 0.0f;
  }
}

extern "C" void kernel_launch(void* const* d_in, const int* in_sizes, int n_in,
                              void* d_out, int out_size, void* d_ws, size_t ws_size,
                              hipStream_t stream) {
  const float* x = (const float*)d_in[0];
  const float* wg = (const float*)d_in[1];

  const int N = in_sizes[0] / HDIM;  // 4096 tokens
  const int K = 2;
  int capacity = (int)floor((double)K * 2.0 * (double)N / (double)NEXP);
  if (capacity < 4) capacity = 4;

  const int S = 2 * N;
  const int nchunk = (S + 63) / 64;  // 128

  float* out = (float*)d_out;
  float* used_cap = out;
  float* cb = out + NEXP;
  float* sec = cb + (size_t)N * NEXP * (size_t)capacity;

  char* ws = (char*)d_ws;
  int* expert_slot = (int*)ws;                              // S ints
  float* prob_slot = (float*)(ws + 4 * (size_t)S);          // S floats
  int* counts = (int*)(ws + 8 * (size_t)S);                 // nchunk*NEXP
  int* base = (int*)(ws + 8 * (size_t)S + 4 * (size_t)(nchunk * NEXP));

  // Zero exactly the logical output: 4*(8 + 2*N*NEXP*C) = 536.9 MB via the
  // rocclr fill path (6.2 TB/s; our own streaming stores max out at ~3.5).
  const size_t out_bytes =
      sizeof(float) * ((size_t)NEXP +
                       2ull * (size_t)N * (size_t)NEXP * (size_t)capacity);
  hipMemsetAsync(d_out, 0, out_bytes, stream);

  logits_topk_kernel<<<(N + 3) / 4, 256, 0, stream>>>(x, wg, expert_slot,
                                                      prob_slot, N);
  count_kernel<<<(S + 255) / 256, 256, 0, stream>>>(expert_slot, counts, S);
  scan_kernel<<<1, 512, 0, stream>>>(counts, base, used_cap, nchunk, capacity);
  scatter_kernel<<<(S + 255) / 256, 256, 0, stream>>>(expert_slot, prob_slot,
                                                      base, cb, sec, N,
                                                      capacity);
}